// Round 1
// baseline (581.768 us; speedup 1.0000x reference)
//
#include <hip/hip_runtime.h>
#include <cstdint>

typedef unsigned short u16;
typedef unsigned int u32;

#define V_N 500000
#define G_N 25000
#define F_N 256
#define GP_N 25088  // G padded to multiple of 128 for GEMM tiles

typedef __attribute__((ext_vector_type(8))) __bf16 bf16x8;
typedef __attribute__((ext_vector_type(4))) float f32x4;

__device__ __forceinline__ u16 f2bf(float f) {
  u32 u = __builtin_bit_cast(u32, f);
  u += 0x7fffu + ((u >> 16) & 1u);
  return (u16)(u >> 16);
}
__device__ __forceinline__ float bf2f(u16 s) {
  u32 u = ((u32)s) << 16;
  return __builtin_bit_cast(float, u);
}

__device__ __forceinline__ void load_lds16(const void* g, void* l) {
  __builtin_amdgcn_global_load_lds(
      (const __attribute__((address_space(1))) void*)g,
      (__attribute__((address_space(3))) void*)l, 16, 0, 0);
}

// ---------------- weight conversion: Wp -> bf16, build combined GRU weight W3 ----------------
// W3[t] is (1024 x 512) bf16, row j, col k:
//   j in [0,512):   k<256 -> Wih[t][j][k],        k>=256 -> Whh[t][j][k-256]   (r,z gates summed)
//   j in [512,768): k<256 -> Wih[t][j][k],        k>=256 -> 0                  (inn)
//   j in [768,1024):k<256 -> 0,                   k>=256 -> Whh[t][j-256][k-256] (hn)
__global__ __launch_bounds__(256) void k_convw(const float* __restrict__ Wp,
                                               const float* __restrict__ Wih,
                                               const float* __restrict__ Whh,
                                               u16* __restrict__ Wpb, u16* __restrict__ W3) {
  int i = blockIdx.x * 256 + threadIdx.x;
  const int NP = 2 * F_N * F_N;  // 131072
  if (i < NP) {
    Wpb[i] = f2bf(Wp[i]);
    return;
  }
  int j = i - NP;  // < 2*1024*512
  int t = j >> 19;
  int r = j & 524287;
  int row = r >> 9;
  int k = r & 511;
  float v;
  if (row < 512) {
    v = (k < 256) ? Wih[t * 196608 + row * 256 + k] : Whh[t * 196608 + row * 256 + (k - 256)];
  } else if (row < 768) {
    v = (k < 256) ? Wih[t * 196608 + row * 256 + k] : 0.f;
  } else {
    v = (k >= 256) ? Whh[t * 196608 + (row - 256) * 256 + (k - 256)] : 0.f;
  }
  W3[j] = f2bf(v);
}

// ---------------- segment offsets from sorted seg_ids ----------------
__global__ __launch_bounds__(256) void k_offsets(const int* __restrict__ seg, int* __restrict__ off) {
  int v = blockIdx.x * 256 + threadIdx.x;
  if (v > V_N) return;
  if (v == 0) {
    int c = seg[0];
    for (int g = 0; g <= c; ++g) off[g] = 0;
  } else if (v == V_N) {
    int pr = seg[V_N - 1];
    for (int g = pr + 1; g <= G_N; ++g) off[g] = V_N;
  } else {
    int pr = seg[v - 1], c = seg[v];
    for (int g = pr + 1; g <= c; ++g) off[g] = v;
  }
}

// ---------------- node pass: g0 = segment_sum(x), q_t = x . wl2_t, xb = bf16(x) ----------------
template <int USEXB>
__global__ __launch_bounds__(256) void k_node_pass(const float* __restrict__ nf,
                                                   const int* __restrict__ off,
                                                   const float* __restrict__ Wl,
                                                   u16* __restrict__ xb,
                                                   float* __restrict__ q0, float* __restrict__ q1,
                                                   float* __restrict__ g0) {
  int g = blockIdx.x;
  int tid = threadIdx.x, lane = tid & 63, w = tid >> 6;
  float w0[4], w1[4];
#pragma unroll
  for (int j = 0; j < 4; ++j) {
    w0[j] = Wl[256 + lane * 4 + j];        // Wl[0][0][F + f]
    w1[j] = Wl[512 + 256 + lane * 4 + j];  // Wl[1][0][F + f]
  }
  int s = off[g], e = off[g + 1];
  float a0 = 0.f, a1 = 0.f, a2 = 0.f, a3 = 0.f;
  for (int v = s + w; v < e; v += 4) {
    const float4 x = *reinterpret_cast<const float4*>(nf + (size_t)v * F_N + lane * 4);
    a0 += x.x; a1 += x.y; a2 += x.z; a3 += x.w;
    if (USEXB) {
      uint2 pk;
      pk.x = (u32)f2bf(x.x) | ((u32)f2bf(x.y) << 16);
      pk.y = (u32)f2bf(x.z) | ((u32)f2bf(x.w) << 16);
      *reinterpret_cast<uint2*>(xb + (size_t)v * F_N + lane * 4) = pk;
    }
    float d0 = x.x * w0[0] + x.y * w0[1] + x.z * w0[2] + x.w * w0[3];
    float d1 = x.x * w1[0] + x.y * w1[1] + x.z * w1[2] + x.w * w1[3];
#pragma unroll
    for (int m = 32; m >= 1; m >>= 1) {
      d0 += __shfl_xor(d0, m, 64);
      d1 += __shfl_xor(d1, m, 64);
    }
    if (lane == 0) { q0[v] = d0; q1[v] = d1; }
  }
  __shared__ float red[4][256];
  red[w][lane * 4 + 0] = a0;
  red[w][lane * 4 + 1] = a1;
  red[w][lane * 4 + 2] = a2;
  red[w][lane * 4 + 3] = a3;
  __syncthreads();
  g0[(size_t)g * F_N + tid] = red[0][tid] + red[1][tid] + red[2][tid] + red[3][tid];
}

// ---------------- block reduction helpers ----------------
__device__ __forceinline__ float blk_sum(float v, float* lds4) {
#pragma unroll
  for (int m = 32; m >= 1; m >>= 1) v += __shfl_xor(v, m, 64);
  __syncthreads();
  if ((threadIdx.x & 63) == 0) lds4[threadIdx.x >> 6] = v;
  __syncthreads();
  return lds4[0] + lds4[1] + lds4[2] + lds4[3];
}
__device__ __forceinline__ float blk_max(float v, float* lds4) {
#pragma unroll
  for (int m = 32; m >= 1; m >>= 1) v = fmaxf(v, __shfl_xor(v, m, 64));
  __syncthreads();
  if ((threadIdx.x & 63) == 0) lds4[threadIdx.x >> 6] = v;
  __syncthreads();
  return fmaxf(fmaxf(lds4[0], lds4[1]), fmaxf(lds4[2], lds4[3]));
}

// ---------------- per-graph attention: softmax over z, s = sum a_v x_v ----------------
template <int USEXB>
__global__ __launch_bounds__(256) void k_attn(const float* __restrict__ h,
                                              const u16* __restrict__ xb, const float* __restrict__ nf,
                                              const float* __restrict__ q, const int* __restrict__ off,
                                              const float* __restrict__ Wl, const float* __restrict__ bl,
                                              int t, u16* __restrict__ sb, float* __restrict__ Ag) {
  int g = blockIdx.x;
  int tid = threadIdx.x, lane = tid & 63, w = tid >> 6;
  __shared__ float lds4[4];
  __shared__ float a_s[256];
  __shared__ float red[4][256];

  // p = dot(relu(h[g]), wl1_t) + bl_t
  float hv = fmaxf(h[(size_t)g * F_N + tid], 0.f);
  float p = blk_sum(hv * Wl[t * 512 + tid], lds4) + bl[t];

  int s = off[g], n = off[g + 1] - s;
  if (n == 0) {
    sb[(size_t)g * F_N + tid] = 0;  // +0.0 bf16
    if (tid == 0) Ag[g] = 0.f;
    return;
  }
  float mloc = -3.4e38f;
  for (int i = tid; i < n; i += 256) {
    float z = p + q[s + i];
    z = z >= 0.f ? z : 0.01f * z;
    mloc = fmaxf(mloc, z);
  }
  float mx = blk_max(mloc, lds4);
  float dloc = 0.f;
  for (int i = tid; i < n; i += 256) {
    float z = p + q[s + i];
    z = z >= 0.f ? z : 0.01f * z;
    dloc += __expf(z - mx);
  }
  float inv = 1.f / blk_sum(dloc, lds4);

  float acc[4] = {0.f, 0.f, 0.f, 0.f};
  for (int c0 = 0; c0 < n; c0 += 256) {
    int cnt = min(256, n - c0);
    __syncthreads();
    if (tid < cnt) {
      float z = p + q[s + c0 + tid];
      z = z >= 0.f ? z : 0.01f * z;
      a_s[tid] = __expf(z - mx) * inv;
    }
    __syncthreads();
    for (int j = w; j < cnt; j += 4) {
      float a = a_s[j];
      size_t base = (size_t)(s + c0 + j) * F_N + lane * 4;
      if (USEXB) {
        uint2 u = *reinterpret_cast<const uint2*>(xb + base);
        acc[0] += a * bf2f((u16)(u.x & 0xffff));
        acc[1] += a * bf2f((u16)(u.x >> 16));
        acc[2] += a * bf2f((u16)(u.y & 0xffff));
        acc[3] += a * bf2f((u16)(u.y >> 16));
      } else {
        float4 x = *reinterpret_cast<const float4*>(nf + base);
        acc[0] += a * x.x; acc[1] += a * x.y; acc[2] += a * x.z; acc[3] += a * x.w;
      }
    }
  }
  __syncthreads();
  red[w][lane * 4 + 0] = acc[0];
  red[w][lane * 4 + 1] = acc[1];
  red[w][lane * 4 + 2] = acc[2];
  red[w][lane * 4 + 3] = acc[3];
  __syncthreads();
  float sv = red[0][tid] + red[1][tid] + red[2][tid] + red[3][tid];
  sb[(size_t)g * F_N + tid] = f2bf(sv);
  if (tid == 0) Ag[g] = 1.f;
}

// ---------------- bf16 MFMA GEMM: C[m][n] = sum_k A[m][k] * B[n][k] ----------------
// mode 0: write fp32 C (ld = N)
// mode 1: v = acc + Ag[m]*bias[n]; elu; write bf16 into Cb at row stride 512 (X2 cols 0..255)
__global__ __launch_bounds__(256) void k_gemm(const u16* __restrict__ A, const u16* __restrict__ B,
                                              int K, int N, float* __restrict__ Cf,
                                              u16* __restrict__ Cb, const float* __restrict__ Ag,
                                              const float* __restrict__ bias, int mode) {
  __shared__ __align__(16) u16 As[128 * 64];
  __shared__ __align__(16) u16 Bs[128 * 64];
  int tid = threadIdx.x, lane = tid & 63, w = tid >> 6;
  int m0 = blockIdx.x * 128, n0 = blockIdx.y * 128;
  int wm = w >> 1, wn = w & 1;
  f32x4 zero = {0.f, 0.f, 0.f, 0.f};
  f32x4 acc[4][4];
#pragma unroll
  for (int i = 0; i < 4; ++i)
#pragma unroll
    for (int j = 0; j < 4; ++j) acc[i][j] = zero;

  int rowA = tid >> 3;          // + c*32
  int col8 = (tid & 7) * 8;
  for (int k0 = 0; k0 < K; k0 += 64) {
    __syncthreads();
#pragma unroll
    for (int c = 0; c < 4; ++c) {
      int r = c * 32 + rowA;
      const u16* gA = A + (size_t)(m0 + r) * K + k0 + col8;
      const u16* gB = B + (size_t)(n0 + r) * K + k0 + col8;
      char* lA = (char*)As + (c * 256 + w * 64) * 16;
      char* lB = (char*)Bs + (c * 256 + w * 64) * 16;
      load_lds16(gA, lA);
      load_lds16(gB, lB);
    }
    __syncthreads();
#pragma unroll
    for (int kk = 0; kk < 64; kk += 32) {
      bf16x8 af[4], bfr[4];
#pragma unroll
      for (int i = 0; i < 4; ++i) {
        af[i] = *reinterpret_cast<const bf16x8*>(&As[(wm * 64 + i * 16 + (lane & 15)) * 64 + kk + (lane >> 4) * 8]);
        bfr[i] = *reinterpret_cast<const bf16x8*>(&Bs[(wn * 64 + i * 16 + (lane & 15)) * 64 + kk + (lane >> 4) * 8]);
      }
#pragma unroll
      for (int i = 0; i < 4; ++i)
#pragma unroll
        for (int j = 0; j < 4; ++j)
          acc[i][j] = __builtin_amdgcn_mfma_f32_16x16x32_bf16(af[i], bfr[j], acc[i][j], 0, 0, 0);
    }
  }
  int crow0 = m0 + wm * 64 + (lane >> 4) * 4;
  int ccol0 = n0 + wn * 64 + (lane & 15);
#pragma unroll
  for (int i = 0; i < 4; ++i)
#pragma unroll
    for (int j = 0; j < 4; ++j) {
      int col = ccol0 + j * 16;
#pragma unroll
      for (int r = 0; r < 4; ++r) {
        int row = crow0 + i * 16 + r;
        float v = acc[i][j][r];
        if (mode == 0) {
          Cf[(size_t)row * N + col] = v;
        } else {
          v += Ag[row] * bias[col];
          v = v > 0.f ? v : (__expf(v) - 1.f);  // elu
          Cb[(size_t)row * 512 + col] = f2bf(v);
        }
      }
    }
}

// ---------------- convert h (fp32) into X2's hb half ----------------
__global__ __launch_bounds__(256) void k_hconv(const float* __restrict__ h, u16* __restrict__ x2) {
  int idx = blockIdx.x * 256 + threadIdx.x;
  if (idx >= GP_N * F_N) return;
  int g = idx >> 8, c = idx & 255;
  x2[(size_t)g * 512 + 256 + c] = f2bf(h[idx]);
}

// ---------------- GRU gates ----------------
__global__ __launch_bounds__(256) void k_gates(const float* __restrict__ OUT, const float* __restrict__ hold,
                                               const float* __restrict__ bih, const float* __restrict__ bhh,
                                               float* __restrict__ hnew, u16* __restrict__ x2, int writehb) {
  int idx = blockIdx.x * 256 + threadIdx.x;
  if (idx >= G_N * F_N) return;
  int g = idx >> 8, c = idx & 255;
  const float* o = OUT + (size_t)g * 1024;
  float ir = o[c] + bih[c] + bhh[c];
  float iz = o[256 + c] + bih[256 + c] + bhh[256 + c];
  float nn = o[512 + c] + bih[512 + c];
  float hn = o[768 + c] + bhh[512 + c];
  float r = 1.f / (1.f + __expf(-ir));
  float z = 1.f / (1.f + __expf(-iz));
  float n = tanhf(nn + r * hn);
  float h0 = hold[idx];
  float hN = (1.f - z) * n + z * h0;
  hnew[idx] = hN;
  if (writehb) x2[(size_t)g * 512 + 256 + c] = f2bf(hN);
}

extern "C" void kernel_launch(void* const* d_in, const int* in_sizes, int n_in,
                              void* d_out, int out_size, void* d_ws, size_t ws_size,
                              hipStream_t stream) {
  const float* nf = (const float*)d_in[0];
  const int* seg = (const int*)d_in[1];
  const float* Wl = (const float*)d_in[2];
  const float* bl = (const float*)d_in[3];
  const float* Wp = (const float*)d_in[4];
  const float* bp = (const float*)d_in[5];
  const float* Wih = (const float*)d_in[6];
  const float* Whh = (const float*)d_in[7];
  const float* bih = (const float*)d_in[8];
  const float* bhh = (const float*)d_in[9];
  float* out = (float*)d_out;

  char* p = (char*)d_ws;
  auto alloc = [&](size_t bytes) {
    char* r = p;
    p += (bytes + 511) & ~(size_t)511;
    return r;
  };
  float* q0 = (float*)alloc((size_t)V_N * 4);
  float* q1 = (float*)alloc((size_t)V_N * 4);
  int* off = (int*)alloc((size_t)(G_N + 1) * 4);
  float* hbuf = (float*)alloc((size_t)GP_N * F_N * 4);
  u16* sb = (u16*)alloc((size_t)GP_N * F_N * 2);
  float* Ag = (float*)alloc((size_t)GP_N * 4);
  u16* X2 = (u16*)alloc((size_t)GP_N * 512 * 2);
  float* OUTb = (float*)alloc((size_t)GP_N * 1024 * 4);
  u16* Wpb = (u16*)alloc((size_t)2 * F_N * F_N * 2);
  u16* W3 = (u16*)alloc((size_t)2 * 1024 * 512 * 2);
  size_t fixed = (size_t)(p - (char*)d_ws);
  bool usexb = (fixed + (size_t)V_N * F_N * 2) <= ws_size;
  u16* xb = usexb ? (u16*)alloc((size_t)V_N * F_N * 2) : nullptr;

  k_convw<<<4608, 256, 0, stream>>>(Wp, Wih, Whh, Wpb, W3);
  k_offsets<<<(V_N + 1 + 255) / 256, 256, 0, stream>>>(seg, off);
  if (usexb)
    k_node_pass<1><<<G_N, 256, 0, stream>>>(nf, off, Wl, xb, q0, q1, hbuf);
  else
    k_node_pass<0><<<G_N, 256, 0, stream>>>(nf, off, Wl, xb, q0, q1, hbuf);
  k_hconv<<<GP_N, 256, 0, stream>>>(hbuf, X2);

  for (int t = 0; t < 2; ++t) {
    const float* q = t ? q1 : q0;
    if (usexb)
      k_attn<1><<<G_N, 256, 0, stream>>>(hbuf, xb, nf, q, off, Wl, bl, t, sb, Ag);
    else
      k_attn<0><<<G_N, 256, 0, stream>>>(hbuf, xb, nf, q, off, Wl, bl, t, sb, Ag);
    // g_repr/context: (GP x 256) = sb @ Wp[t]^T, +Ag*bp, elu -> X2[:, 0:256]
    k_gemm<<<dim3(GP_N / 128, 2), 256, 0, stream>>>(sb, Wpb + t * 65536, 256, 256,
                                                    nullptr, X2, Ag, bp + t * 256, 1);
    // GRU pre-activations: (GP x 1024) = X2 @ W3[t]^T -> OUTb
    k_gemm<<<dim3(GP_N / 128, 8), 256, 0, stream>>>(X2, W3 + (size_t)t * 524288, 512, 1024,
                                                    OUTb, nullptr, nullptr, nullptr, 0);
    k_gates<<<G_N, 256, 0, stream>>>(OUTb, hbuf, bih + t * 768, bhh + t * 768,
                                     (t == 1) ? out : hbuf, X2, (t == 0) ? 1 : 0);
  }
}

// Round 3
// 520.741 us; speedup vs baseline: 1.1172x; 1.1172x over previous
//
#include <hip/hip_runtime.h>
#include <cstdint>

typedef unsigned short u16;
typedef unsigned int u32;

#define V_N 500000
#define G_N 25000
#define F_N 256
#define GP_N 25088  // G padded to multiple of 128 for GEMM tiles
#define CAP 64      // LDS row-cache capacity for fused t=0 attention

typedef __attribute__((ext_vector_type(8))) __bf16 bf16x8;
typedef __attribute__((ext_vector_type(4))) float f32x4;

__device__ __forceinline__ u16 f2bf(float f) {
  u32 u = __builtin_bit_cast(u32, f);
  u += 0x7fffu + ((u >> 16) & 1u);
  return (u16)(u >> 16);
}
__device__ __forceinline__ float bf2f(u16 s) {
  u32 u = ((u32)s) << 16;
  return __builtin_bit_cast(float, u);
}
__device__ __forceinline__ float sigm(float x) { return 1.f / (1.f + __expf(-x)); }
__device__ __forceinline__ float tanh_fast(float x) {
  return 1.f - 2.f / (__expf(2.f * x) + 1.f);  // saturates correctly
}

__device__ __forceinline__ void load_lds16(const void* g, void* l) {
  __builtin_amdgcn_global_load_lds(
      (const __attribute__((address_space(1))) void*)g,
      (__attribute__((address_space(3))) void*)l, 16, 0, 0);
}

// ---------------- weight conversion ----------------
// Wp -> bf16 (unchanged layout), W3 gate-interleaved:
// row = (c>>4)*64 + gate*16 + (c&15); cols 0..255 multiply ctx, 256..511 multiply h.
//   gate0 (r):  [Wih[c]      | Whh[c]      ]
//   gate1 (z):  [Wih[256+c]  | Whh[256+c]  ]
//   gate2 (in): [Wih[512+c]  | 0           ]
//   gate3 (hn): [0           | Whh[512+c]  ]
__global__ __launch_bounds__(256) void k_convw(const float* __restrict__ Wp,
                                               const float* __restrict__ Wih,
                                               const float* __restrict__ Whh,
                                               u16* __restrict__ Wpb, u16* __restrict__ W3) {
  int i = blockIdx.x * 256 + threadIdx.x;
  const int NP = 2 * F_N * F_N;  // 131072
  if (i < NP) {
    Wpb[i] = f2bf(Wp[i]);
    return;
  }
  int j = i - NP;  // < 2*1024*512
  int t = j >> 19;
  int r = j & 524287;
  int row = r >> 9;
  int k = r & 511;
  int q = row >> 6;
  int gate = (row >> 4) & 3;
  int c = q * 16 + (row & 15);
  const float* wi = Wih + t * 196608;
  const float* wh = Whh + t * 196608;
  float v;
  if (gate == 0) {
    v = (k < 256) ? wi[c * 256 + k] : wh[c * 256 + (k - 256)];
  } else if (gate == 1) {
    v = (k < 256) ? wi[(256 + c) * 256 + k] : wh[(256 + c) * 256 + (k - 256)];
  } else if (gate == 2) {
    v = (k < 256) ? wi[(512 + c) * 256 + k] : 0.f;
  } else {
    v = (k >= 256) ? wh[(512 + c) * 256 + (k - 256)] : 0.f;
  }
  W3[j] = f2bf(v);
}

// ---------------- segment offsets from sorted seg_ids ----------------
__global__ __launch_bounds__(256) void k_offsets(const int* __restrict__ seg, int* __restrict__ off) {
  int v = blockIdx.x * 256 + threadIdx.x;
  if (v > V_N) return;
  if (v == 0) {
    int c = seg[0];
    for (int g = 0; g <= c; ++g) off[g] = 0;
  } else if (v == V_N) {
    int pr = seg[V_N - 1];
    for (int g = pr + 1; g <= G_N; ++g) off[g] = V_N;
  } else {
    int pr = seg[v - 1], c = seg[v];
    for (int g = pr + 1; g <= c; ++g) off[g] = v;
  }
}

// ---------------- block reduction helpers ----------------
__device__ __forceinline__ float blk_sum(float v, float* lds4) {
#pragma unroll
  for (int m = 32; m >= 1; m >>= 1) v += __shfl_xor(v, m, 64);
  __syncthreads();
  if ((threadIdx.x & 63) == 0) lds4[threadIdx.x >> 6] = v;
  __syncthreads();
  return lds4[0] + lds4[1] + lds4[2] + lds4[3];
}
__device__ __forceinline__ float blk_max(float v, float* lds4) {
#pragma unroll
  for (int m = 32; m >= 1; m >>= 1) v = fmaxf(v, __shfl_xor(v, m, 64));
  __syncthreads();
  if ((threadIdx.x & 63) == 0) lds4[threadIdx.x >> 6] = v;
  __syncthreads();
  return fmaxf(fmaxf(lds4[0], lds4[1]), fmaxf(lds4[2], lds4[3]));
}

// ---------------- fused node pass (+ t=0 attention) ----------------
template <int USEXB>
__global__ __launch_bounds__(256) void k_node_fused(const float* __restrict__ nf,
                                                    const int* __restrict__ off,
                                                    const float* __restrict__ Wl,
                                                    const float* __restrict__ bl,
                                                    u16* __restrict__ xb,
                                                    float* __restrict__ q0, float* __restrict__ q1,
                                                    float* __restrict__ hbuf0, u16* __restrict__ x2a,
                                                    u16* __restrict__ x2b,
                                                    u16* __restrict__ sb, float* __restrict__ Ag) {
  int g = blockIdx.x;
  int tid = threadIdx.x, lane = tid & 63, w = tid >> 6;
  if (g >= G_N) {  // padding cleanup (rows read by GEMMs)
    hbuf0[(size_t)g * F_N + tid] = 0.f;
    x2a[(size_t)g * 512 + 256 + tid] = 0;
    x2b[(size_t)g * 512 + 256 + tid] = 0;
    sb[(size_t)g * F_N + tid] = 0;
    if (tid == 0) Ag[g] = 0.f;
    return;
  }
  __shared__ __align__(16) u16 xcache[CAP * F_N];  // 32 KB
  __shared__ float zrow[CAP];
  __shared__ float red[4][256];
  __shared__ float a_s[256];
  __shared__ float lds4[4];

  float w0[4], w1[4];
#pragma unroll
  for (int j = 0; j < 4; ++j) {
    w0[j] = Wl[256 + lane * 4 + j];        // Wl[0][0][F + f]
    w1[j] = Wl[512 + 256 + lane * 4 + j];  // Wl[1][0][F + f]
  }
  int s = off[g], e = off[g + 1];
  int n = e - s;
  float a0 = 0.f, a1 = 0.f, a2 = 0.f, a3 = 0.f;
  for (int v = s + w; v < e; v += 4) {
    const float4 x = *reinterpret_cast<const float4*>(nf + (size_t)v * F_N + lane * 4);
    a0 += x.x; a1 += x.y; a2 += x.z; a3 += x.w;
    uint2 pk;
    pk.x = (u32)f2bf(x.x) | ((u32)f2bf(x.y) << 16);
    pk.y = (u32)f2bf(x.z) | ((u32)f2bf(x.w) << 16);
    if (USEXB) *reinterpret_cast<uint2*>(xb + (size_t)v * F_N + lane * 4) = pk;
    int li = v - s;
    if (li < CAP) *reinterpret_cast<uint2*>(&xcache[li * F_N + lane * 4]) = pk;
    float d0 = x.x * w0[0] + x.y * w0[1] + x.z * w0[2] + x.w * w0[3];
    float d1 = x.x * w1[0] + x.y * w1[1] + x.z * w1[2] + x.w * w1[3];
#pragma unroll
    for (int m = 32; m >= 1; m >>= 1) {
      d0 += __shfl_xor(d0, m, 64);
      d1 += __shfl_xor(d1, m, 64);
    }
    if (lane == 0) {
      q0[v] = d0;
      q1[v] = d1;
      if (li < CAP) zrow[li] = d0;
    }
  }
  red[w][lane * 4 + 0] = a0;
  red[w][lane * 4 + 1] = a1;
  red[w][lane * 4 + 2] = a2;
  red[w][lane * 4 + 3] = a3;
  __threadfence_block();  // q0/xb visibility for the (rare) n>CAP fallback
  __syncthreads();
  float sval = red[0][tid] + red[1][tid] + red[2][tid] + red[3][tid];
  hbuf0[(size_t)g * F_N + tid] = sval;
  x2a[(size_t)g * 512 + 256 + tid] = f2bf(sval);

  // ---- fused t=0 attention ----
  float p = blk_sum(fmaxf(sval, 0.f) * Wl[tid], lds4) + bl[0];
  if (n == 0) {
    sb[(size_t)g * F_N + tid] = 0;
    if (tid == 0) Ag[g] = 0.f;
    return;
  }
  float mloc = -3.4e38f;
  for (int i = tid; i < n; i += 256) {
    float zq = (i < CAP) ? zrow[i] : q0[s + i];
    float z = p + zq;
    z = z >= 0.f ? z : 0.01f * z;
    mloc = fmaxf(mloc, z);
  }
  float mx = blk_max(mloc, lds4);
  float dloc = 0.f;
  for (int i = tid; i < n; i += 256) {
    float zq = (i < CAP) ? zrow[i] : q0[s + i];
    float z = p + zq;
    z = z >= 0.f ? z : 0.01f * z;
    dloc += __expf(z - mx);
  }
  float inv = 1.f / blk_sum(dloc, lds4);

  float acc4[4] = {0.f, 0.f, 0.f, 0.f};
  for (int c0 = 0; c0 < n; c0 += 256) {
    int cnt = min(256, n - c0);
    __syncthreads();
    if (tid < cnt) {
      int i = c0 + tid;
      float zq = (i < CAP) ? zrow[i] : q0[s + i];
      float z = p + zq;
      z = z >= 0.f ? z : 0.01f * z;
      a_s[tid] = __expf(z - mx) * inv;
    }
    __syncthreads();
    for (int j = w; j < cnt; j += 4) {
      int i = c0 + j;
      float a = a_s[j];
      uint2 u;
      if (i < CAP) {
        u = *reinterpret_cast<const uint2*>(&xcache[i * F_N + lane * 4]);
      } else if (USEXB) {
        u = *reinterpret_cast<const uint2*>(xb + (size_t)(s + i) * F_N + lane * 4);
      } else {
        float4 x = *reinterpret_cast<const float4*>(nf + (size_t)(s + i) * F_N + lane * 4);
        acc4[0] += a * x.x; acc4[1] += a * x.y; acc4[2] += a * x.z; acc4[3] += a * x.w;
        continue;
      }
      acc4[0] += a * bf2f((u16)(u.x & 0xffff));
      acc4[1] += a * bf2f((u16)(u.x >> 16));
      acc4[2] += a * bf2f((u16)(u.y & 0xffff));
      acc4[3] += a * bf2f((u16)(u.y >> 16));
    }
  }
  __syncthreads();
  red[w][lane * 4 + 0] = acc4[0];
  red[w][lane * 4 + 1] = acc4[1];
  red[w][lane * 4 + 2] = acc4[2];
  red[w][lane * 4 + 3] = acc4[3];
  __syncthreads();
  float sv = red[0][tid] + red[1][tid] + red[2][tid] + red[3][tid];
  sb[(size_t)g * F_N + tid] = f2bf(sv);
  if (tid == 0) Ag[g] = 1.f;
}

// ---------------- per-graph attention (t=1) ----------------
template <int USEXB>
__global__ __launch_bounds__(256) void k_attn(const float* __restrict__ h,
                                              const u16* __restrict__ xb, const float* __restrict__ nf,
                                              const float* __restrict__ q, const int* __restrict__ off,
                                              const float* __restrict__ Wl, const float* __restrict__ bl,
                                              int t, u16* __restrict__ sb, float* __restrict__ Ag) {
  int g = blockIdx.x;
  int tid = threadIdx.x, lane = tid & 63, w = tid >> 6;
  __shared__ float lds4[4];
  __shared__ float a_s[256];
  __shared__ float red[4][256];

  float hv = fmaxf(h[(size_t)g * F_N + tid], 0.f);
  float p = blk_sum(hv * Wl[t * 512 + tid], lds4) + bl[t];

  int s = off[g], n = off[g + 1] - s;
  if (n == 0) {
    sb[(size_t)g * F_N + tid] = 0;
    if (tid == 0) Ag[g] = 0.f;
    return;
  }
  float mloc = -3.4e38f;
  for (int i = tid; i < n; i += 256) {
    float z = p + q[s + i];
    z = z >= 0.f ? z : 0.01f * z;
    mloc = fmaxf(mloc, z);
  }
  float mx = blk_max(mloc, lds4);
  float dloc = 0.f;
  for (int i = tid; i < n; i += 256) {
    float z = p + q[s + i];
    z = z >= 0.f ? z : 0.01f * z;
    dloc += __expf(z - mx);
  }
  float inv = 1.f / blk_sum(dloc, lds4);

  float acc[4] = {0.f, 0.f, 0.f, 0.f};
  for (int c0 = 0; c0 < n; c0 += 256) {
    int cnt = min(256, n - c0);
    __syncthreads();
    if (tid < cnt) {
      float z = p + q[s + c0 + tid];
      z = z >= 0.f ? z : 0.01f * z;
      a_s[tid] = __expf(z - mx) * inv;
    }
    __syncthreads();
    for (int j = w; j < cnt; j += 4) {
      float a = a_s[j];
      size_t base = (size_t)(s + c0 + j) * F_N + lane * 4;
      if (USEXB) {
        uint2 u = *reinterpret_cast<const uint2*>(xb + base);
        acc[0] += a * bf2f((u16)(u.x & 0xffff));
        acc[1] += a * bf2f((u16)(u.x >> 16));
        acc[2] += a * bf2f((u16)(u.y & 0xffff));
        acc[3] += a * bf2f((u16)(u.y >> 16));
      } else {
        float4 x = *reinterpret_cast<const float4*>(nf + base);
        acc[0] += a * x.x; acc[1] += a * x.y; acc[2] += a * x.z; acc[3] += a * x.w;
      }
    }
  }
  __syncthreads();
  red[w][lane * 4 + 0] = acc[0];
  red[w][lane * 4 + 1] = acc[1];
  red[w][lane * 4 + 2] = acc[2];
  red[w][lane * 4 + 3] = acc[3];
  __syncthreads();
  float sv = red[0][tid] + red[1][tid] + red[2][tid] + red[3][tid];
  sb[(size_t)g * F_N + tid] = f2bf(sv);
  if (tid == 0) Ag[g] = 1.f;
}

// ---------------- bf16 MFMA GEMM: C[m][n] = sum_k A[m][k] * B[n][k] ----------------
// mode 1 (ctx):  v = acc + AgH[row]*b1[col]; elu; x2out[row*512 + col] = bf16(v)
// mode 2 (GRU):  cols gate-interleaved; full GRU in epilogue; dst fp32
//                (+x2out h-half bf16 if writehb). dst/x2out MUST differ from
//                A/AgH sources (no same-launch read-write aliasing).
__global__ __launch_bounds__(256) void k_gemm(const u16* __restrict__ A, const u16* __restrict__ B,
                                              int K, float* __restrict__ dst,
                                              u16* __restrict__ x2out, const float* __restrict__ AgH,
                                              const float* __restrict__ b1, const float* __restrict__ b2,
                                              int mode, int writehb) {
  __shared__ __align__(16) u16 As[128 * 64];
  __shared__ __align__(16) u16 Bs[128 * 64];
  int tid = threadIdx.x, lane = tid & 63, w = tid >> 6;
  int m0 = blockIdx.x * 128, n0 = blockIdx.y * 128;
  int wm = w >> 1, wn = w & 1;
  f32x4 zero = {0.f, 0.f, 0.f, 0.f};
  f32x4 acc[4][4];
#pragma unroll
  for (int i = 0; i < 4; ++i)
#pragma unroll
    for (int j = 0; j < 4; ++j) acc[i][j] = zero;

  int rowA = tid >> 3;
  int col8 = (tid & 7) * 8;
  for (int k0 = 0; k0 < K; k0 += 64) {
    __syncthreads();
#pragma unroll
    for (int c = 0; c < 4; ++c) {
      int r = c * 32 + rowA;
      const u16* gA = A + (size_t)(m0 + r) * K + k0 + col8;
      const u16* gB = B + (size_t)(n0 + r) * K + k0 + col8;
      char* lA = (char*)As + (c * 256 + w * 64) * 16;
      char* lB = (char*)Bs + (c * 256 + w * 64) * 16;
      load_lds16(gA, lA);
      load_lds16(gB, lB);
    }
    __syncthreads();
#pragma unroll
    for (int kk = 0; kk < 64; kk += 32) {
      bf16x8 af[4], bfr[4];
#pragma unroll
      for (int i = 0; i < 4; ++i) {
        af[i] = *reinterpret_cast<const bf16x8*>(&As[(wm * 64 + i * 16 + (lane & 15)) * 64 + kk + (lane >> 4) * 8]);
        bfr[i] = *reinterpret_cast<const bf16x8*>(&Bs[(wn * 64 + i * 16 + (lane & 15)) * 64 + kk + (lane >> 4) * 8]);
      }
#pragma unroll
      for (int i = 0; i < 4; ++i)
#pragma unroll
        for (int j = 0; j < 4; ++j)
          acc[i][j] = __builtin_amdgcn_mfma_f32_16x16x32_bf16(af[i], bfr[j], acc[i][j], 0, 0, 0);
    }
  }
  int crow0 = m0 + wm * 64 + (lane >> 4) * 4;
  if (mode == 1) {
    int ccol0 = n0 + wn * 64 + (lane & 15);
#pragma unroll
    for (int i = 0; i < 4; ++i)
#pragma unroll
      for (int j = 0; j < 4; ++j) {
        int col = ccol0 + j * 16;
#pragma unroll
        for (int r = 0; r < 4; ++r) {
          int row = crow0 + i * 16 + r;
          float v = acc[i][j][r] + AgH[row] * b1[col];
          v = v > 0.f ? v : (__expf(v) - 1.f);  // elu
          x2out[(size_t)row * 512 + col] = f2bf(v);
        }
      }
  } else {
    int qgrp = blockIdx.y * 2 + wn;
    int c = qgrp * 16 + (lane & 15);
    float bi0 = b1[c] + b2[c];
    float bi1 = b1[256 + c] + b2[256 + c];
    float bi2 = b1[512 + c];
    float bi3 = b2[512 + c];
#pragma unroll
    for (int i = 0; i < 4; ++i)
#pragma unroll
      for (int r = 0; r < 4; ++r) {
        int grow = crow0 + i * 16 + r;
        if (grow >= G_N) continue;
        float ir = acc[i][0][r] + bi0;
        float iz = acc[i][1][r] + bi1;
        float nn = acc[i][2][r] + bi2;
        float hn = acc[i][3][r] + bi3;
        float rg = sigm(ir);
        float zg = sigm(iz);
        float h0 = AgH[(size_t)grow * F_N + c];  // AgH = h_old (different buffer!)
        float nv = tanh_fast(nn + rg * hn);
        float hN = (1.f - zg) * nv + zg * h0;
        dst[(size_t)grow * F_N + c] = hN;
        if (writehb) x2out[(size_t)grow * 512 + 256 + c] = f2bf(hN);
      }
  }
}

extern "C" void kernel_launch(void* const* d_in, const int* in_sizes, int n_in,
                              void* d_out, int out_size, void* d_ws, size_t ws_size,
                              hipStream_t stream) {
  const float* nf = (const float*)d_in[0];
  const int* seg = (const int*)d_in[1];
  const float* Wl = (const float*)d_in[2];
  const float* bl = (const float*)d_in[3];
  const float* Wp = (const float*)d_in[4];
  const float* bp = (const float*)d_in[5];
  const float* Wih = (const float*)d_in[6];
  const float* Whh = (const float*)d_in[7];
  const float* bih = (const float*)d_in[8];
  const float* bhh = (const float*)d_in[9];
  float* out = (float*)d_out;

  char* p = (char*)d_ws;
  auto alloc = [&](size_t bytes) {
    char* r = p;
    p += (bytes + 511) & ~(size_t)511;
    return r;
  };
  float* q0 = (float*)alloc((size_t)V_N * 4);
  float* q1 = (float*)alloc((size_t)V_N * 4);
  int* off = (int*)alloc((size_t)(G_N + 1) * 4);
  float* hbuf0 = (float*)alloc((size_t)GP_N * F_N * 4);
  float* hbuf1 = (float*)alloc((size_t)GP_N * F_N * 4);
  u16* sb = (u16*)alloc((size_t)GP_N * F_N * 2);
  float* Ag = (float*)alloc((size_t)GP_N * 4);
  u16* X2a = (u16*)alloc((size_t)GP_N * 512 * 2);
  u16* X2b = (u16*)alloc((size_t)GP_N * 512 * 2);
  u16* Wpb = (u16*)alloc((size_t)2 * F_N * F_N * 2);
  u16* W3 = (u16*)alloc((size_t)2 * 1024 * 512 * 2);
  size_t fixed = (size_t)(p - (char*)d_ws);
  bool usexb = (fixed + (size_t)V_N * F_N * 2) <= ws_size;
  u16* xb = usexb ? (u16*)alloc((size_t)V_N * F_N * 2) : nullptr;

  k_convw<<<4608, 256, 0, stream>>>(Wp, Wih, Whh, Wpb, W3);
  k_offsets<<<(V_N + 1 + 255) / 256, 256, 0, stream>>>(seg, off);
  if (usexb)
    k_node_fused<1><<<GP_N, 256, 0, stream>>>(nf, off, Wl, bl, xb, q0, q1, hbuf0, X2a, X2b, sb, Ag);
  else
    k_node_fused<0><<<GP_N, 256, 0, stream>>>(nf, off, Wl, bl, xb, q0, q1, hbuf0, X2a, X2b, sb, Ag);

  // ---- t = 0 ----
  k_gemm<<<dim3(GP_N / 128, 2), 256, 0, stream>>>(sb, Wpb, 256,
                                                  nullptr, X2a, Ag, bp, nullptr, 1, 0);
  k_gemm<<<dim3(GP_N / 128, 8), 256, 0, stream>>>(X2a, W3, 512,
                                                  hbuf1, X2b, hbuf0,
                                                  bih, bhh, 2, 1);
  // ---- t = 1 ----
  if (usexb)
    k_attn<1><<<G_N, 256, 0, stream>>>(hbuf1, xb, nf, q1, off, Wl, bl, 1, sb, Ag);
  else
    k_attn<0><<<G_N, 256, 0, stream>>>(hbuf1, xb, nf, q1, off, Wl, bl, 1, sb, Ag);
  k_gemm<<<dim3(GP_N / 128, 2), 256, 0, stream>>>(sb, Wpb + 65536, 256,
                                                  nullptr, X2b, Ag, bp + 256, nullptr, 1, 0);
  k_gemm<<<dim3(GP_N / 128, 8), 256, 0, stream>>>(X2b, W3 + 524288, 512,
                                                  out, nullptr, hbuf1,
                                                  bih + 768, bhh + 768, 2, 0);
}

// Round 4
// 510.752 us; speedup vs baseline: 1.1390x; 1.0196x over previous
//
#include <hip/hip_runtime.h>
#include <cstdint>

typedef unsigned short u16;
typedef unsigned int u32;

#define V_N 500000
#define G_N 25000
#define F_N 256
#define GP_N 25088  // G padded to multiple of 128 for GEMM tiles

typedef __attribute__((ext_vector_type(8))) __bf16 bf16x8;
typedef __attribute__((ext_vector_type(4))) float f32x4;

__device__ __forceinline__ u16 f2bf(float f) {
  u32 u = __builtin_bit_cast(u32, f);
  u += 0x7fffu + ((u >> 16) & 1u);
  return (u16)(u >> 16);
}
__device__ __forceinline__ float bf2f(u16 s) {
  u32 u = ((u32)s) << 16;
  return __builtin_bit_cast(float, u);
}
__device__ __forceinline__ float sigm(float x) { return 1.f / (1.f + __expf(-x)); }
__device__ __forceinline__ float tanh_fast(float x) {
  return 1.f - 2.f / (__expf(2.f * x) + 1.f);
}
__device__ __forceinline__ float lrelu(float z) { return z >= 0.f ? z : 0.01f * z; }

__device__ __forceinline__ void load_lds16(const void* g, void* l) {
  __builtin_amdgcn_global_load_lds(
      (const __attribute__((address_space(1))) void*)g,
      (__attribute__((address_space(3))) void*)l, 16, 0, 0);
}

// ---------------- weight conversion (unchanged, verified r3) ----------------
__global__ __launch_bounds__(256) void k_convw(const float* __restrict__ Wp,
                                               const float* __restrict__ Wih,
                                               const float* __restrict__ Whh,
                                               u16* __restrict__ Wpb, u16* __restrict__ W3) {
  int i = blockIdx.x * 256 + threadIdx.x;
  const int NP = 2 * F_N * F_N;  // 131072
  if (i < NP) {
    Wpb[i] = f2bf(Wp[i]);
    return;
  }
  int j = i - NP;  // < 2*1024*512
  int t = j >> 19;
  int r = j & 524287;
  int row = r >> 9;
  int k = r & 511;
  int q = row >> 6;
  int gate = (row >> 4) & 3;
  int c = q * 16 + (row & 15);
  const float* wi = Wih + t * 196608;
  const float* wh = Whh + t * 196608;
  float v;
  if (gate == 0) {
    v = (k < 256) ? wi[c * 256 + k] : wh[c * 256 + (k - 256)];
  } else if (gate == 1) {
    v = (k < 256) ? wi[(256 + c) * 256 + k] : wh[(256 + c) * 256 + (k - 256)];
  } else if (gate == 2) {
    v = (k < 256) ? wi[(512 + c) * 256 + k] : 0.f;
  } else {
    v = (k >= 256) ? wh[(512 + c) * 256 + (k - 256)] : 0.f;
  }
  W3[j] = f2bf(v);
}

// ---------------- segment offsets from sorted seg_ids ----------------
__global__ __launch_bounds__(256) void k_offsets(const int* __restrict__ seg, int* __restrict__ off) {
  int v = blockIdx.x * 256 + threadIdx.x;
  if (v > V_N) return;
  if (v == 0) {
    int c = seg[0];
    for (int g = 0; g <= c; ++g) off[g] = 0;
  } else if (v == V_N) {
    int pr = seg[V_N - 1];
    for (int g = pr + 1; g <= G_N; ++g) off[g] = V_N;
  } else {
    int pr = seg[v - 1], c = seg[v];
    for (int g = pr + 1; g <= c; ++g) off[g] = v;
  }
}

// ---------------- node pass: wave-per-graph, no barriers, no LDS ----------------
// lane holds feature cols lane*4..+3. Per row: float4 load, per-lane segment
// sums, q0/q1 dots via wave shfl-reduce. Writes xb (bf16), q0,q1, hbuf0 (fp32
// h0), x2a h-half (bf16). Padding waves zero GEMM-visible rows.
__global__ __launch_bounds__(256) void k_node(const float* __restrict__ nf,
                                              const int* __restrict__ off,
                                              const float* __restrict__ Wl,
                                              u16* __restrict__ xb,
                                              float* __restrict__ q0, float* __restrict__ q1,
                                              float* __restrict__ hbuf0, u16* __restrict__ x2a,
                                              u16* __restrict__ x2b,
                                              u16* __restrict__ sb, float* __restrict__ Ag) {
  int g = blockIdx.x * 4 + (threadIdx.x >> 6);
  int lane = threadIdx.x & 63;
  if (g >= GP_N) return;
  if (g >= G_N) {  // padding cleanup
    float4 z4 = {0.f, 0.f, 0.f, 0.f};
    uint2 z2 = {0u, 0u};
    *reinterpret_cast<float4*>(hbuf0 + (size_t)g * F_N + lane * 4) = z4;
    *reinterpret_cast<uint2*>(x2a + (size_t)g * 512 + 256 + lane * 4) = z2;
    *reinterpret_cast<uint2*>(x2b + (size_t)g * 512 + 256 + lane * 4) = z2;
    *reinterpret_cast<uint2*>(sb + (size_t)g * F_N + lane * 4) = z2;
    if (lane == 0) Ag[g] = 0.f;
    return;
  }
  const float4 w0 = *reinterpret_cast<const float4*>(Wl + 256 + lane * 4);
  const float4 w1 = *reinterpret_cast<const float4*>(Wl + 768 + lane * 4);
  int s = off[g], e = off[g + 1];
  float a0 = 0.f, a1 = 0.f, a2 = 0.f, a3 = 0.f;
  for (int v = s; v < e; ++v) {
    const float4 x = *reinterpret_cast<const float4*>(nf + (size_t)v * F_N + lane * 4);
    a0 += x.x; a1 += x.y; a2 += x.z; a3 += x.w;
    uint2 pk;
    pk.x = (u32)f2bf(x.x) | ((u32)f2bf(x.y) << 16);
    pk.y = (u32)f2bf(x.z) | ((u32)f2bf(x.w) << 16);
    *reinterpret_cast<uint2*>(xb + (size_t)v * F_N + lane * 4) = pk;
    float d0 = x.x * w0.x + x.y * w0.y + x.z * w0.z + x.w * w0.w;
    float d1 = x.x * w1.x + x.y * w1.y + x.z * w1.z + x.w * w1.w;
#pragma unroll
    for (int m = 32; m >= 1; m >>= 1) {
      d0 += __shfl_xor(d0, m, 64);
      d1 += __shfl_xor(d1, m, 64);
    }
    if (lane == 0) {
      q0[v] = d0;
      q1[v] = d1;
    }
  }
  float4 h4 = {a0, a1, a2, a3};
  *reinterpret_cast<float4*>(hbuf0 + (size_t)g * F_N + lane * 4) = h4;
  uint2 hs;
  hs.x = (u32)f2bf(a0) | ((u32)f2bf(a1) << 16);
  hs.y = (u32)f2bf(a2) | ((u32)f2bf(a3) << 16);
  *reinterpret_cast<uint2*>(x2a + (size_t)g * 512 + 256 + lane * 4) = hs;
}

// ---------------- attention: wave-per-graph ----------------
// p = relu(h[g]).Wl[t] + bl[t]; softmax over z_i = lrelu(p + q_i); weighted
// feature sum, 2 rows/iteration (lane-half <-> row parity, 16B/lane loads).
__global__ __launch_bounds__(256) void k_attn(const float* __restrict__ h,
                                              const u16* __restrict__ xb,
                                              const float* __restrict__ q,
                                              const int* __restrict__ off,
                                              const float* __restrict__ Wl,
                                              const float* __restrict__ bl, int t,
                                              u16* __restrict__ sb, float* __restrict__ Ag) {
  int g = blockIdx.x * 4 + (threadIdx.x >> 6);
  int lane = threadIdx.x & 63;
  if (g >= G_N) return;

  const float4 hv = *reinterpret_cast<const float4*>(h + (size_t)g * F_N + lane * 4);
  const float4 wv = *reinterpret_cast<const float4*>(Wl + t * 512 + lane * 4);
  float pd = fmaxf(hv.x, 0.f) * wv.x + fmaxf(hv.y, 0.f) * wv.y +
             fmaxf(hv.z, 0.f) * wv.z + fmaxf(hv.w, 0.f) * wv.w;
#pragma unroll
  for (int m = 32; m >= 1; m >>= 1) pd += __shfl_xor(pd, m, 64);
  float p = pd + bl[t];

  int s = off[g], n = off[g + 1] - s;
  if (n == 0) {
    if (lane < 32) {
      uint4 z = {0u, 0u, 0u, 0u};
      *reinterpret_cast<uint4*>(sb + (size_t)g * F_N + lane * 8) = z;
    }
    if (lane == 0) Ag[g] = 0.f;
    return;
  }
  float mloc = -3.4e38f;
  for (int i = lane; i < n; i += 64) mloc = fmaxf(mloc, lrelu(p + q[s + i]));
#pragma unroll
  for (int m = 32; m >= 1; m >>= 1) mloc = fmaxf(mloc, __shfl_xor(mloc, m, 64));
  float mx = mloc;
  float dloc = 0.f;
  for (int i = lane; i < n; i += 64) dloc += __expf(lrelu(p + q[s + i]) - mx);
#pragma unroll
  for (int m = 32; m >= 1; m >>= 1) dloc += __shfl_xor(dloc, m, 64);
  float inv = 1.f / dloc;

  int half = lane >> 5;        // 0: even rows, 1: odd rows
  int cl = (lane & 31) * 8;    // 8 bf16 cols per lane
  float acc[8] = {0.f, 0.f, 0.f, 0.f, 0.f, 0.f, 0.f, 0.f};
  for (int i = 0; i < n; i += 2) {
    int r = i + half;
    float a = 0.f;
    int row = s;  // safe row for OOB lanes
    if (r < n) {
      a = __expf(lrelu(p + q[s + r]) - mx) * inv;
      row = s + r;
    }
    uint4 x = *reinterpret_cast<const uint4*>(xb + (size_t)row * F_N + cl);
    acc[0] += a * bf2f((u16)(x.x & 0xffff));
    acc[1] += a * bf2f((u16)(x.x >> 16));
    acc[2] += a * bf2f((u16)(x.y & 0xffff));
    acc[3] += a * bf2f((u16)(x.y >> 16));
    acc[4] += a * bf2f((u16)(x.z & 0xffff));
    acc[5] += a * bf2f((u16)(x.z >> 16));
    acc[6] += a * bf2f((u16)(x.w & 0xffff));
    acc[7] += a * bf2f((u16)(x.w >> 16));
  }
#pragma unroll
  for (int k = 0; k < 8; ++k) acc[k] += __shfl_xor(acc[k], 32, 64);
  if (lane < 32) {
    uint4 o;
    o.x = (u32)f2bf(acc[0]) | ((u32)f2bf(acc[1]) << 16);
    o.y = (u32)f2bf(acc[2]) | ((u32)f2bf(acc[3]) << 16);
    o.z = (u32)f2bf(acc[4]) | ((u32)f2bf(acc[5]) << 16);
    o.w = (u32)f2bf(acc[6]) | ((u32)f2bf(acc[7]) << 16);
    *reinterpret_cast<uint4*>(sb + (size_t)g * F_N + cl) = o;
  }
  if (lane == 0) Ag[g] = 1.f;
}

// ---------------- bf16 MFMA GEMM (unchanged, verified r3) ----------------
// mode 1 (ctx):  v = acc + AgH[row]*b1[col]; elu; x2out[row*512 + col] = bf16(v)
// mode 2 (GRU):  cols gate-interleaved; full GRU in epilogue; dst fp32
//                (+x2out h-half bf16 if writehb). dst/x2out differ from sources.
__global__ __launch_bounds__(256) void k_gemm(const u16* __restrict__ A, const u16* __restrict__ B,
                                              int K, float* __restrict__ dst,
                                              u16* __restrict__ x2out, const float* __restrict__ AgH,
                                              const float* __restrict__ b1, const float* __restrict__ b2,
                                              int mode, int writehb) {
  __shared__ __align__(16) u16 As[128 * 64];
  __shared__ __align__(16) u16 Bs[128 * 64];
  int tid = threadIdx.x, lane = tid & 63, w = tid >> 6;
  int m0 = blockIdx.x * 128, n0 = blockIdx.y * 128;
  int wm = w >> 1, wn = w & 1;
  f32x4 zero = {0.f, 0.f, 0.f, 0.f};
  f32x4 acc[4][4];
#pragma unroll
  for (int i = 0; i < 4; ++i)
#pragma unroll
    for (int j = 0; j < 4; ++j) acc[i][j] = zero;

  int rowA = tid >> 3;
  int col8 = (tid & 7) * 8;
  for (int k0 = 0; k0 < K; k0 += 64) {
    __syncthreads();
#pragma unroll
    for (int c = 0; c < 4; ++c) {
      int r = c * 32 + rowA;
      const u16* gA = A + (size_t)(m0 + r) * K + k0 + col8;
      const u16* gB = B + (size_t)(n0 + r) * K + k0 + col8;
      char* lA = (char*)As + (c * 256 + w * 64) * 16;
      char* lB = (char*)Bs + (c * 256 + w * 64) * 16;
      load_lds16(gA, lA);
      load_lds16(gB, lB);
    }
    __syncthreads();
#pragma unroll
    for (int kk = 0; kk < 64; kk += 32) {
      bf16x8 af[4], bfr[4];
#pragma unroll
      for (int i = 0; i < 4; ++i) {
        af[i] = *reinterpret_cast<const bf16x8*>(&As[(wm * 64 + i * 16 + (lane & 15)) * 64 + kk + (lane >> 4) * 8]);
        bfr[i] = *reinterpret_cast<const bf16x8*>(&Bs[(wn * 64 + i * 16 + (lane & 15)) * 64 + kk + (lane >> 4) * 8]);
      }
#pragma unroll
      for (int i = 0; i < 4; ++i)
#pragma unroll
        for (int j = 0; j < 4; ++j)
          acc[i][j] = __builtin_amdgcn_mfma_f32_16x16x32_bf16(af[i], bfr[j], acc[i][j], 0, 0, 0);
    }
  }
  int crow0 = m0 + wm * 64 + (lane >> 4) * 4;
  if (mode == 1) {
    int ccol0 = n0 + wn * 64 + (lane & 15);
#pragma unroll
    for (int i = 0; i < 4; ++i)
#pragma unroll
      for (int j = 0; j < 4; ++j) {
        int col = ccol0 + j * 16;
#pragma unroll
        for (int r = 0; r < 4; ++r) {
          int row = crow0 + i * 16 + r;
          float v = acc[i][j][r] + AgH[row] * b1[col];
          v = v > 0.f ? v : (__expf(v) - 1.f);  // elu
          x2out[(size_t)row * 512 + col] = f2bf(v);
        }
      }
  } else {
    int qgrp = blockIdx.y * 2 + wn;
    int c = qgrp * 16 + (lane & 15);
    float bi0 = b1[c] + b2[c];
    float bi1 = b1[256 + c] + b2[256 + c];
    float bi2 = b1[512 + c];
    float bi3 = b2[512 + c];
#pragma unroll
    for (int i = 0; i < 4; ++i)
#pragma unroll
      for (int r = 0; r < 4; ++r) {
        int grow = crow0 + i * 16 + r;
        if (grow >= G_N) continue;
        float ir = acc[i][0][r] + bi0;
        float iz = acc[i][1][r] + bi1;
        float nn = acc[i][2][r] + bi2;
        float hn = acc[i][3][r] + bi3;
        float rg = sigm(ir);
        float zg = sigm(iz);
        float h0 = AgH[(size_t)grow * F_N + c];
        float nv = tanh_fast(nn + rg * hn);
        float hN = (1.f - zg) * nv + zg * h0;
        dst[(size_t)grow * F_N + c] = hN;
        if (writehb) x2out[(size_t)grow * 512 + 256 + c] = f2bf(hN);
      }
  }
}

extern "C" void kernel_launch(void* const* d_in, const int* in_sizes, int n_in,
                              void* d_out, int out_size, void* d_ws, size_t ws_size,
                              hipStream_t stream) {
  const float* nf = (const float*)d_in[0];
  const int* seg = (const int*)d_in[1];
  const float* Wl = (const float*)d_in[2];
  const float* bl = (const float*)d_in[3];
  const float* Wp = (const float*)d_in[4];
  const float* bp = (const float*)d_in[5];
  const float* Wih = (const float*)d_in[6];
  const float* Whh = (const float*)d_in[7];
  const float* bih = (const float*)d_in[8];
  const float* bhh = (const float*)d_in[9];
  float* out = (float*)d_out;

  char* p = (char*)d_ws;
  auto alloc = [&](size_t bytes) {
    char* r = p;
    p += (bytes + 511) & ~(size_t)511;
    return r;
  };
  float* q0 = (float*)alloc((size_t)V_N * 4);
  float* q1 = (float*)alloc((size_t)V_N * 4);
  int* off = (int*)alloc((size_t)(G_N + 1) * 4);
  float* hbuf0 = (float*)alloc((size_t)GP_N * F_N * 4);
  float* hbuf1 = (float*)alloc((size_t)GP_N * F_N * 4);
  u16* sb = (u16*)alloc((size_t)GP_N * F_N * 2);
  float* Ag = (float*)alloc((size_t)GP_N * 4);
  u16* X2a = (u16*)alloc((size_t)GP_N * 512 * 2);
  u16* X2b = (u16*)alloc((size_t)GP_N * 512 * 2);
  u16* Wpb = (u16*)alloc((size_t)2 * F_N * F_N * 2);
  u16* W3 = (u16*)alloc((size_t)2 * 1024 * 512 * 2);
  u16* xb = (u16*)alloc((size_t)V_N * F_N * 2);

  k_convw<<<4608, 256, 0, stream>>>(Wp, Wih, Whh, Wpb, W3);
  k_offsets<<<(V_N + 1 + 255) / 256, 256, 0, stream>>>(seg, off);
  k_node<<<GP_N / 4, 256, 0, stream>>>(nf, off, Wl, xb, q0, q1, hbuf0, X2a, X2b, sb, Ag);

  // ---- t = 0 ----
  k_attn<<<G_N / 4, 256, 0, stream>>>(hbuf0, xb, q0, off, Wl, bl, 0, sb, Ag);
  k_gemm<<<dim3(GP_N / 128, 2), 256, 0, stream>>>(sb, Wpb, 256,
                                                  nullptr, X2a, Ag, bp, nullptr, 1, 0);
  k_gemm<<<dim3(GP_N / 128, 8), 256, 0, stream>>>(X2a, W3, 512,
                                                  hbuf1, X2b, hbuf0, bih, bhh, 2, 1);
  // ---- t = 1 ----
  k_attn<<<G_N / 4, 256, 0, stream>>>(hbuf1, xb, q1, off, Wl, bl, 1, sb, Ag);
  k_gemm<<<dim3(GP_N / 128, 2), 256, 0, stream>>>(sb, Wpb + 65536, 256,
                                                  nullptr, X2b, Ag, bp + 256, nullptr, 1, 0);
  k_gemm<<<dim3(GP_N / 128, 8), 256, 0, stream>>>(X2b, W3 + 524288, 512,
                                                  out, nullptr, hbuf1, bih + 768, bhh + 768, 2, 0);
}

// Round 5
// 467.165 us; speedup vs baseline: 1.2453x; 1.0933x over previous
//
#include <hip/hip_runtime.h>
#include <cstdint>

typedef unsigned short u16;
typedef unsigned int u32;

#define V_N 500000
#define G_N 25000
#define F_N 256
#define GP_N 25088  // G padded to multiple of 128 for GEMM tiles

typedef __attribute__((ext_vector_type(8))) __bf16 bf16x8;
typedef __attribute__((ext_vector_type(4))) float f32x4;

__device__ __forceinline__ u16 f2bf(float f) {
  u32 u = __builtin_bit_cast(u32, f);
  u += 0x7fffu + ((u >> 16) & 1u);
  return (u16)(u >> 16);
}
__device__ __forceinline__ float bf2f(u16 s) {
  u32 u = ((u32)s) << 16;
  return __builtin_bit_cast(float, u);
}
__device__ __forceinline__ float sigm(float x) { return 1.f / (1.f + __expf(-x)); }
__device__ __forceinline__ float tanh_fast(float x) {
  return 1.f - 2.f / (__expf(2.f * x) + 1.f);
}
__device__ __forceinline__ float lrelu(float z) { return z >= 0.f ? z : 0.01f * z; }

__device__ __forceinline__ void load_lds16(const void* g, void* l) {
  __builtin_amdgcn_global_load_lds(
      (const __attribute__((address_space(1))) void*)g,
      (__attribute__((address_space(3))) void*)l, 16, 0, 0);
}

// ---------------- prep: weight conversion + segment offsets (merged) ----------------
// blocks [0,4608): Wp->bf16 and gate-interleaved W3 (verified r3)
// blocks [4608,..): offsets from sorted seg_ids
#define CONVW_BLK 4608
#define OFFS_BLK ((V_N + 1 + 255) / 256)
__global__ __launch_bounds__(256) void k_prep(const float* __restrict__ Wp,
                                              const float* __restrict__ Wih,
                                              const float* __restrict__ Whh,
                                              u16* __restrict__ Wpb, u16* __restrict__ W3,
                                              const int* __restrict__ seg, int* __restrict__ off) {
  if (blockIdx.x >= CONVW_BLK) {
    int v = (blockIdx.x - CONVW_BLK) * 256 + threadIdx.x;
    if (v > V_N) return;
    if (v == 0) {
      int c = seg[0];
      for (int g = 0; g <= c; ++g) off[g] = 0;
    } else if (v == V_N) {
      int pr = seg[V_N - 1];
      for (int g = pr + 1; g <= G_N; ++g) off[g] = V_N;
    } else {
      int pr = seg[v - 1], c = seg[v];
      for (int g = pr + 1; g <= c; ++g) off[g] = v;
    }
    return;
  }
  int i = blockIdx.x * 256 + threadIdx.x;
  const int NP = 2 * F_N * F_N;  // 131072
  if (i < NP) {
    Wpb[i] = f2bf(Wp[i]);
    return;
  }
  int j = i - NP;  // < 2*1024*512
  int t = j >> 19;
  int r = j & 524287;
  int row = r >> 9;
  int k = r & 511;
  int q = row >> 6;
  int gate = (row >> 4) & 3;
  int c = q * 16 + (row & 15);
  const float* wi = Wih + t * 196608;
  const float* wh = Whh + t * 196608;
  float v;
  if (gate == 0) {
    v = (k < 256) ? wi[c * 256 + k] : wh[c * 256 + (k - 256)];
  } else if (gate == 1) {
    v = (k < 256) ? wi[(256 + c) * 256 + k] : wh[(256 + c) * 256 + (k - 256)];
  } else if (gate == 2) {
    v = (k < 256) ? wi[(512 + c) * 256 + k] : 0.f;
  } else {
    v = (k >= 256) ? wh[(512 + c) * 256 + (k - 256)] : 0.f;
  }
  W3[j] = f2bf(v);
}

// ---------------- fused node pass + t=0 attention (wave-per-graph) ----------------
// Streaming loop (2-row unroll): segment sums, q0/q1 dots (full shfl-reduce
// broadcast), xb bf16 write. Lane r captures q0 of row r in a register.
// Then t=0 softmax entirely in registers (n<=64 fast path) and the weighted
// feature sum re-reads this wave's own L2-hot xb rows (ordered by vmcnt(0)).
__global__ __launch_bounds__(256) void k_node_fused(const float* __restrict__ nf,
                                                    const int* __restrict__ off,
                                                    const float* __restrict__ Wl,
                                                    const float* __restrict__ bl,
                                                    u16* __restrict__ xb,
                                                    float* __restrict__ q0, float* __restrict__ q1,
                                                    float* __restrict__ hbuf0, u16* __restrict__ x2a,
                                                    u16* __restrict__ x2b,
                                                    u16* __restrict__ sb, float* __restrict__ Ag) {
  int g = blockIdx.x * 4 + (threadIdx.x >> 6);
  int lane = threadIdx.x & 63;
  if (g >= GP_N) return;
  if (g >= G_N) {  // padding cleanup
    float4 z4 = {0.f, 0.f, 0.f, 0.f};
    uint2 z2 = {0u, 0u};
    *reinterpret_cast<float4*>(hbuf0 + (size_t)g * F_N + lane * 4) = z4;
    *reinterpret_cast<uint2*>(x2a + (size_t)g * 512 + 256 + lane * 4) = z2;
    *reinterpret_cast<uint2*>(x2b + (size_t)g * 512 + 256 + lane * 4) = z2;
    *reinterpret_cast<uint2*>(sb + (size_t)g * F_N + lane * 4) = z2;
    if (lane == 0) Ag[g] = 0.f;
    return;
  }
  const float4 w0 = *reinterpret_cast<const float4*>(Wl + 256 + lane * 4);
  const float4 w1 = *reinterpret_cast<const float4*>(Wl + 768 + lane * 4);
  const float4 wh = *reinterpret_cast<const float4*>(Wl + lane * 4);  // t0 h-part
  int s = off[g], e = off[g + 1];
  int n = e - s;
  float a0 = 0.f, a1 = 0.f, a2 = 0.f, a3 = 0.f;
  float qreg = 0.f;
  int v = s;
  for (; v + 2 <= e; v += 2) {
    const float4 xA = *reinterpret_cast<const float4*>(nf + (size_t)v * F_N + lane * 4);
    const float4 xB = *reinterpret_cast<const float4*>(nf + (size_t)(v + 1) * F_N + lane * 4);
    a0 += xA.x + xB.x; a1 += xA.y + xB.y; a2 += xA.z + xB.z; a3 += xA.w + xB.w;
    uint2 pA, pB;
    pA.x = (u32)f2bf(xA.x) | ((u32)f2bf(xA.y) << 16);
    pA.y = (u32)f2bf(xA.z) | ((u32)f2bf(xA.w) << 16);
    pB.x = (u32)f2bf(xB.x) | ((u32)f2bf(xB.y) << 16);
    pB.y = (u32)f2bf(xB.z) | ((u32)f2bf(xB.w) << 16);
    *reinterpret_cast<uint2*>(xb + (size_t)v * F_N + lane * 4) = pA;
    *reinterpret_cast<uint2*>(xb + (size_t)(v + 1) * F_N + lane * 4) = pB;
    float dA0 = xA.x * w0.x + xA.y * w0.y + xA.z * w0.z + xA.w * w0.w;
    float dA1 = xA.x * w1.x + xA.y * w1.y + xA.z * w1.z + xA.w * w1.w;
    float dB0 = xB.x * w0.x + xB.y * w0.y + xB.z * w0.z + xB.w * w0.w;
    float dB1 = xB.x * w1.x + xB.y * w1.y + xB.z * w1.z + xB.w * w1.w;
#pragma unroll
    for (int m = 32; m >= 1; m >>= 1) {
      dA0 += __shfl_xor(dA0, m, 64);
      dA1 += __shfl_xor(dA1, m, 64);
      dB0 += __shfl_xor(dB0, m, 64);
      dB1 += __shfl_xor(dB1, m, 64);
    }
    if (lane == 0) {
      q0[v] = dA0; q1[v] = dA1;
      q0[v + 1] = dB0; q1[v + 1] = dB1;
    }
    int li = v - s;
    if (li == lane) qreg = dA0;
    if (li + 1 == lane) qreg = dB0;
  }
  if (v < e) {
    const float4 xA = *reinterpret_cast<const float4*>(nf + (size_t)v * F_N + lane * 4);
    a0 += xA.x; a1 += xA.y; a2 += xA.z; a3 += xA.w;
    uint2 pA;
    pA.x = (u32)f2bf(xA.x) | ((u32)f2bf(xA.y) << 16);
    pA.y = (u32)f2bf(xA.z) | ((u32)f2bf(xA.w) << 16);
    *reinterpret_cast<uint2*>(xb + (size_t)v * F_N + lane * 4) = pA;
    float dA0 = xA.x * w0.x + xA.y * w0.y + xA.z * w0.z + xA.w * w0.w;
    float dA1 = xA.x * w1.x + xA.y * w1.y + xA.z * w1.z + xA.w * w1.w;
#pragma unroll
    for (int m = 32; m >= 1; m >>= 1) {
      dA0 += __shfl_xor(dA0, m, 64);
      dA1 += __shfl_xor(dA1, m, 64);
    }
    if (lane == 0) { q0[v] = dA0; q1[v] = dA1; }
    if (v - s == lane) qreg = dA0;
  }
  // h0 outputs
  float4 h4 = {a0, a1, a2, a3};
  *reinterpret_cast<float4*>(hbuf0 + (size_t)g * F_N + lane * 4) = h4;
  uint2 hs;
  hs.x = (u32)f2bf(a0) | ((u32)f2bf(a1) << 16);
  hs.y = (u32)f2bf(a2) | ((u32)f2bf(a3) << 16);
  *reinterpret_cast<uint2*>(x2a + (size_t)g * 512 + 256 + lane * 4) = hs;

  // ---- fused t=0 attention ----
  if (n == 0) {
    if (lane < 32) {
      uint4 z = {0u, 0u, 0u, 0u};
      *reinterpret_cast<uint4*>(sb + (size_t)g * F_N + lane * 8) = z;
    }
    if (lane == 0) Ag[g] = 0.f;
    return;
  }
  float pd = fmaxf(a0, 0.f) * wh.x + fmaxf(a1, 0.f) * wh.y +
             fmaxf(a2, 0.f) * wh.z + fmaxf(a3, 0.f) * wh.w;
#pragma unroll
  for (int m = 32; m >= 1; m >>= 1) pd += __shfl_xor(pd, m, 64);
  float p = pd + bl[0];

  float mx, inv, ee = 0.f;
  bool fast = (n <= 64);
  if (fast) {
    float z = (lane < n) ? lrelu(p + qreg) : -3.4e38f;
    float zm = z;
#pragma unroll
    for (int m = 32; m >= 1; m >>= 1) zm = fmaxf(zm, __shfl_xor(zm, m, 64));
    mx = zm;
    ee = (lane < n) ? __expf(z - mx) : 0.f;
    float d = ee;
#pragma unroll
    for (int m = 32; m >= 1; m >>= 1) d += __shfl_xor(d, m, 64);
    inv = 1.f / d;
    asm volatile("s_waitcnt vmcnt(0)" ::: "memory");  // xb stores -> visible
  } else {
    asm volatile("s_waitcnt vmcnt(0)" ::: "memory");  // q0/xb stores -> visible
    float mloc = -3.4e38f;
    for (int i = lane; i < n; i += 64) mloc = fmaxf(mloc, lrelu(p + q0[s + i]));
#pragma unroll
    for (int m = 32; m >= 1; m >>= 1) mloc = fmaxf(mloc, __shfl_xor(mloc, m, 64));
    mx = mloc;
    float dloc = 0.f;
    for (int i = lane; i < n; i += 64) dloc += __expf(lrelu(p + q0[s + i]) - mx);
#pragma unroll
    for (int m = 32; m >= 1; m >>= 1) dloc += __shfl_xor(dloc, m, 64);
    inv = 1.f / dloc;
  }

  int half = lane >> 5;
  int cl = (lane & 31) * 8;
  float acc[8] = {0.f, 0.f, 0.f, 0.f, 0.f, 0.f, 0.f, 0.f};
  for (int i = 0; i < n; i += 2) {
    int r = i + half;
    float a;
    if (fast) {
      float ev = __shfl(ee, (r < 64 ? r : 63), 64);
      a = (r < n) ? ev * inv : 0.f;
    } else {
      a = (r < n) ? __expf(lrelu(p + q0[s + r]) - mx) * inv : 0.f;
    }
    int row = s + (r < n ? r : 0);
    uint4 x = *reinterpret_cast<const uint4*>(xb + (size_t)row * F_N + cl);
    acc[0] += a * bf2f((u16)(x.x & 0xffff));
    acc[1] += a * bf2f((u16)(x.x >> 16));
    acc[2] += a * bf2f((u16)(x.y & 0xffff));
    acc[3] += a * bf2f((u16)(x.y >> 16));
    acc[4] += a * bf2f((u16)(x.z & 0xffff));
    acc[5] += a * bf2f((u16)(x.z >> 16));
    acc[6] += a * bf2f((u16)(x.w & 0xffff));
    acc[7] += a * bf2f((u16)(x.w >> 16));
  }
#pragma unroll
  for (int k = 0; k < 8; ++k) acc[k] += __shfl_xor(acc[k], 32, 64);
  if (lane < 32) {
    uint4 o;
    o.x = (u32)f2bf(acc[0]) | ((u32)f2bf(acc[1]) << 16);
    o.y = (u32)f2bf(acc[2]) | ((u32)f2bf(acc[3]) << 16);
    o.z = (u32)f2bf(acc[4]) | ((u32)f2bf(acc[5]) << 16);
    o.w = (u32)f2bf(acc[6]) | ((u32)f2bf(acc[7]) << 16);
    *reinterpret_cast<uint4*>(sb + (size_t)g * F_N + cl) = o;
  }
  if (lane == 0) Ag[g] = 1.f;
}

// ---------------- attention t=1: wave-per-graph (verified r4) ----------------
__global__ __launch_bounds__(256) void k_attn(const float* __restrict__ h,
                                              const u16* __restrict__ xb,
                                              const float* __restrict__ q,
                                              const int* __restrict__ off,
                                              const float* __restrict__ Wl,
                                              const float* __restrict__ bl, int t,
                                              u16* __restrict__ sb, float* __restrict__ Ag) {
  int g = blockIdx.x * 4 + (threadIdx.x >> 6);
  int lane = threadIdx.x & 63;
  if (g >= G_N) return;

  const float4 hv = *reinterpret_cast<const float4*>(h + (size_t)g * F_N + lane * 4);
  const float4 wv = *reinterpret_cast<const float4*>(Wl + t * 512 + lane * 4);
  float pd = fmaxf(hv.x, 0.f) * wv.x + fmaxf(hv.y, 0.f) * wv.y +
             fmaxf(hv.z, 0.f) * wv.z + fmaxf(hv.w, 0.f) * wv.w;
#pragma unroll
  for (int m = 32; m >= 1; m >>= 1) pd += __shfl_xor(pd, m, 64);
  float p = pd + bl[t];

  int s = off[g], n = off[g + 1] - s;
  if (n == 0) {
    if (lane < 32) {
      uint4 z = {0u, 0u, 0u, 0u};
      *reinterpret_cast<uint4*>(sb + (size_t)g * F_N + lane * 8) = z;
    }
    if (lane == 0) Ag[g] = 0.f;
    return;
  }
  float mloc = -3.4e38f;
  for (int i = lane; i < n; i += 64) mloc = fmaxf(mloc, lrelu(p + q[s + i]));
#pragma unroll
  for (int m = 32; m >= 1; m >>= 1) mloc = fmaxf(mloc, __shfl_xor(mloc, m, 64));
  float mx = mloc;
  float dloc = 0.f;
  for (int i = lane; i < n; i += 64) dloc += __expf(lrelu(p + q[s + i]) - mx);
#pragma unroll
  for (int m = 32; m >= 1; m >>= 1) dloc += __shfl_xor(dloc, m, 64);
  float inv = 1.f / dloc;

  int half = lane >> 5;
  int cl = (lane & 31) * 8;
  float acc[8] = {0.f, 0.f, 0.f, 0.f, 0.f, 0.f, 0.f, 0.f};
  for (int i = 0; i < n; i += 2) {
    int r = i + half;
    float a = 0.f;
    int row = s;
    if (r < n) {
      a = __expf(lrelu(p + q[s + r]) - mx) * inv;
      row = s + r;
    }
    uint4 x = *reinterpret_cast<const uint4*>(xb + (size_t)row * F_N + cl);
    acc[0] += a * bf2f((u16)(x.x & 0xffff));
    acc[1] += a * bf2f((u16)(x.x >> 16));
    acc[2] += a * bf2f((u16)(x.y & 0xffff));
    acc[3] += a * bf2f((u16)(x.y >> 16));
    acc[4] += a * bf2f((u16)(x.z & 0xffff));
    acc[5] += a * bf2f((u16)(x.z >> 16));
    acc[6] += a * bf2f((u16)(x.w & 0xffff));
    acc[7] += a * bf2f((u16)(x.w >> 16));
  }
#pragma unroll
  for (int k = 0; k < 8; ++k) acc[k] += __shfl_xor(acc[k], 32, 64);
  if (lane < 32) {
    uint4 o;
    o.x = (u32)f2bf(acc[0]) | ((u32)f2bf(acc[1]) << 16);
    o.y = (u32)f2bf(acc[2]) | ((u32)f2bf(acc[3]) << 16);
    o.z = (u32)f2bf(acc[4]) | ((u32)f2bf(acc[5]) << 16);
    o.w = (u32)f2bf(acc[6]) | ((u32)f2bf(acc[7]) << 16);
    *reinterpret_cast<uint4*>(sb + (size_t)g * F_N + cl) = o;
  }
  if (lane == 0) Ag[g] = 1.f;
}

// ---------------- bf16 MFMA GEMM (unchanged, verified r3/r4) ----------------
__global__ __launch_bounds__(256) void k_gemm(const u16* __restrict__ A, const u16* __restrict__ B,
                                              int K, float* __restrict__ dst,
                                              u16* __restrict__ x2out, const float* __restrict__ AgH,
                                              const float* __restrict__ b1, const float* __restrict__ b2,
                                              int mode, int writehb) {
  __shared__ __align__(16) u16 As[128 * 64];
  __shared__ __align__(16) u16 Bs[128 * 64];
  int tid = threadIdx.x, lane = tid & 63, w = tid >> 6;
  int m0 = blockIdx.x * 128, n0 = blockIdx.y * 128;
  int wm = w >> 1, wn = w & 1;
  f32x4 zero = {0.f, 0.f, 0.f, 0.f};
  f32x4 acc[4][4];
#pragma unroll
  for (int i = 0; i < 4; ++i)
#pragma unroll
    for (int j = 0; j < 4; ++j) acc[i][j] = zero;

  int rowA = tid >> 3;
  int col8 = (tid & 7) * 8;
  for (int k0 = 0; k0 < K; k0 += 64) {
    __syncthreads();
#pragma unroll
    for (int c = 0; c < 4; ++c) {
      int r = c * 32 + rowA;
      const u16* gA = A + (size_t)(m0 + r) * K + k0 + col8;
      const u16* gB = B + (size_t)(n0 + r) * K + k0 + col8;
      char* lA = (char*)As + (c * 256 + w * 64) * 16;
      char* lB = (char*)Bs + (c * 256 + w * 64) * 16;
      load_lds16(gA, lA);
      load_lds16(gB, lB);
    }
    __syncthreads();
#pragma unroll
    for (int kk = 0; kk < 64; kk += 32) {
      bf16x8 af[4], bfr[4];
#pragma unroll
      for (int i = 0; i < 4; ++i) {
        af[i] = *reinterpret_cast<const bf16x8*>(&As[(wm * 64 + i * 16 + (lane & 15)) * 64 + kk + (lane >> 4) * 8]);
        bfr[i] = *reinterpret_cast<const bf16x8*>(&Bs[(wn * 64 + i * 16 + (lane & 15)) * 64 + kk + (lane >> 4) * 8]);
      }
#pragma unroll
      for (int i = 0; i < 4; ++i)
#pragma unroll
        for (int j = 0; j < 4; ++j)
          acc[i][j] = __builtin_amdgcn_mfma_f32_16x16x32_bf16(af[i], bfr[j], acc[i][j], 0, 0, 0);
    }
  }
  int crow0 = m0 + wm * 64 + (lane >> 4) * 4;
  if (mode == 1) {
    int ccol0 = n0 + wn * 64 + (lane & 15);
#pragma unroll
    for (int i = 0; i < 4; ++i)
#pragma unroll
      for (int j = 0; j < 4; ++j) {
        int col = ccol0 + j * 16;
#pragma unroll
        for (int r = 0; r < 4; ++r) {
          int row = crow0 + i * 16 + r;
          float v = acc[i][j][r] + AgH[row] * b1[col];
          v = v > 0.f ? v : (__expf(v) - 1.f);  // elu
          x2out[(size_t)row * 512 + col] = f2bf(v);
        }
      }
  } else {
    int qgrp = blockIdx.y * 2 + wn;
    int c = qgrp * 16 + (lane & 15);
    float bi0 = b1[c] + b2[c];
    float bi1 = b1[256 + c] + b2[256 + c];
    float bi2 = b1[512 + c];
    float bi3 = b2[512 + c];
#pragma unroll
    for (int i = 0; i < 4; ++i)
#pragma unroll
      for (int r = 0; r < 4; ++r) {
        int grow = crow0 + i * 16 + r;
        if (grow >= G_N) continue;
        float ir = acc[i][0][r] + bi0;
        float iz = acc[i][1][r] + bi1;
        float nn = acc[i][2][r] + bi2;
        float hn = acc[i][3][r] + bi3;
        float rg = sigm(ir);
        float zg = sigm(iz);
        float h0 = AgH[(size_t)grow * F_N + c];
        float nv = tanh_fast(nn + rg * hn);
        float hN = (1.f - zg) * nv + zg * h0;
        dst[(size_t)grow * F_N + c] = hN;
        if (writehb) x2out[(size_t)grow * 512 + 256 + c] = f2bf(hN);
      }
  }
}

extern "C" void kernel_launch(void* const* d_in, const int* in_sizes, int n_in,
                              void* d_out, int out_size, void* d_ws, size_t ws_size,
                              hipStream_t stream) {
  const float* nf = (const float*)d_in[0];
  const int* seg = (const int*)d_in[1];
  const float* Wl = (const float*)d_in[2];
  const float* bl = (const float*)d_in[3];
  const float* Wp = (const float*)d_in[4];
  const float* bp = (const float*)d_in[5];
  const float* Wih = (const float*)d_in[6];
  const float* Whh = (const float*)d_in[7];
  const float* bih = (const float*)d_in[8];
  const float* bhh = (const float*)d_in[9];
  float* out = (float*)d_out;

  char* p = (char*)d_ws;
  auto alloc = [&](size_t bytes) {
    char* r = p;
    p += (bytes + 511) & ~(size_t)511;
    return r;
  };
  float* q0 = (float*)alloc((size_t)V_N * 4);
  float* q1 = (float*)alloc((size_t)V_N * 4);
  int* off = (int*)alloc((size_t)(G_N + 1) * 4);
  float* hbuf0 = (float*)alloc((size_t)GP_N * F_N * 4);
  float* hbuf1 = (float*)alloc((size_t)GP_N * F_N * 4);
  u16* sb = (u16*)alloc((size_t)GP_N * F_N * 2);
  float* Ag = (float*)alloc((size_t)GP_N * 4);
  u16* X2a = (u16*)alloc((size_t)GP_N * 512 * 2);
  u16* X2b = (u16*)alloc((size_t)GP_N * 512 * 2);
  u16* Wpb = (u16*)alloc((size_t)2 * F_N * F_N * 2);
  u16* W3 = (u16*)alloc((size_t)2 * 1024 * 512 * 2);
  u16* xb = (u16*)alloc((size_t)V_N * F_N * 2);

  k_prep<<<CONVW_BLK + OFFS_BLK, 256, 0, stream>>>(Wp, Wih, Whh, Wpb, W3, seg, off);
  k_node_fused<<<GP_N / 4, 256, 0, stream>>>(nf, off, Wl, bl, xb, q0, q1,
                                             hbuf0, X2a, X2b, sb, Ag);

  // ---- t = 0 ---- (t0 attention already fused into node pass)
  k_gemm<<<dim3(GP_N / 128, 2), 256, 0, stream>>>(sb, Wpb, 256,
                                                  nullptr, X2a, Ag, bp, nullptr, 1, 0);
  k_gemm<<<dim3(GP_N / 128, 8), 256, 0, stream>>>(X2a, W3, 512,
                                                  hbuf1, X2b, hbuf0, bih, bhh, 2, 1);
  // ---- t = 1 ----
  k_attn<<<G_N / 4, 256, 0, stream>>>(hbuf1, xb, q1, off, Wl, bl, 1, sb, Ag);
  k_gemm<<<dim3(GP_N / 128, 2), 256, 0, stream>>>(sb, Wpb + 65536, 256,
                                                  nullptr, X2b, Ag, bp + 256, nullptr, 1, 0);
  k_gemm<<<dim3(GP_N / 128, 8), 256, 0, stream>>>(X2b, W3 + 524288, 512,
                                                  out, nullptr, hbuf1, bih + 768, bhh + 768, 2, 0);
}